// Round 1
// baseline (614.418 us; speedup 1.0000x reference)
//
#include <hip/hip_runtime.h>
#include <stdint.h>

// Problem (fp32 in / fp32 out): out = relu((x + (x@Wv^T+bv)@Wo^T + bo) @ Wn^T + bn)
//   softmax over a single score == 1 -> q,k path is dead code.
// Reformulated: out = relu(x@Wn^T + v@Wm^T + biasTot)
//   v  = x@Wv^T + bv          [8192 x 64]
//   Wm = Wn @ Wo              [4096 x 64]
//   biasTot = bn + Wn @ bo    [4096]
// Round 5: k_main rewritten as 256x256-tile 8-phase deep-pipelined schedule
//   (T2+T3+T4+T5): 512 thr / 8 waves (2Mx4N), per-wave 128x64 out, acc[8][4].
//   LDS = ring of 4 K=32 slices (A 256x32 + B 256x32 = 32KB/slice, 128KB).
//   Per slice: 2 phases {ds_read frags || issue 2 gl_lds16 (slice s+2) ||
//   barrier; lgkmcnt(0); setprio(1); 16 MFMA; setprio(0); barrier}.
//   Boundary wait = counted s_waitcnt vmcnt(4) (never 0 until tail).
//   Swizzle: LDS[row][slot16B] = global[row][slot ^ ((row>>1)&3)] on 64B rows.
//   Rank-64 V/Wm correction = slices 128,129 (lda=64). Aux kernels unchanged.

typedef unsigned short u16;
typedef float f32x4 __attribute__((ext_vector_type(4)));
typedef __bf16 bf16x8 __attribute__((ext_vector_type(8)));
typedef u16 u16x8 __attribute__((ext_vector_type(8)));

__device__ __forceinline__ float b2f(u16 u) {
  union { unsigned int i; float f; } x; x.i = ((unsigned int)u) << 16; return x.f;
}
__device__ __forceinline__ u16 f2b(float f) {  // round-to-nearest-even
  union { float f; unsigned int i; } x; x.f = f;
  unsigned int r = x.i + 0x7FFFu + ((x.i >> 16) & 1u);
  return (u16)(r >> 16);
}

// async global->LDS, 16B per lane; lds base wave-uniform (lane lands at base + lane*16B)
__device__ __forceinline__ void gl_lds16(const u16* g, u16* l) {
#if __has_builtin(__builtin_amdgcn_global_load_lds)
  __builtin_amdgcn_global_load_lds((__attribute__((address_space(1))) void*)g,
                                   (__attribute__((address_space(3))) void*)l, 16, 0, 0);
#else
  int lane = threadIdx.x & 63;
  *(u16x8*)(l + lane * 8) = *(const u16x8*)g;
#endif
}

__device__ __forceinline__ f32x4 mfma16(bf16x8 a, bf16x8 b, f32x4 c) {
  return __builtin_amdgcn_mfma_f32_16x16x32_bf16(a, b, c, 0, 0, 0);
}

// ---------------------------------------------------------------------------
// k_cvt: fp32 -> bf16 for x (33.5M), Wn (16.7M), Wv (262K). 8 floats/thread.
// (identical to round 2)
// ---------------------------------------------------------------------------
#define XCH 4194304L   // 33554432/8
#define WNCH 2097152L  // 16777216/8
__global__ __launch_bounds__(256) void k_cvt(
    const float* __restrict__ x, const float* __restrict__ Wn, const float* __restrict__ Wv,
    u16* __restrict__ xb, u16* __restrict__ Wnb, u16* __restrict__ Wvb) {
  long i = (long)blockIdx.x * 256 + threadIdx.x;
  const float* src; u16* dst; long off;
  if (i < XCH) { src = x; dst = xb; off = i * 8; }
  else if (i < XCH + WNCH) { src = Wn; dst = Wnb; off = (i - XCH) * 8; }
  else { src = Wv; dst = Wvb; off = (i - XCH - WNCH) * 8; }
  f32x4 a = *(const f32x4*)&src[off];
  f32x4 b = *(const f32x4*)&src[off + 4];
  u16x8 o;
#pragma unroll
  for (int e = 0; e < 4; ++e) { o[e] = f2b(a[e]); o[4 + e] = f2b(b[e]); }
  *(u16x8*)&dst[off] = o;
}

// ---------------------------------------------------------------------------
// kT: WoT[a][k] = bf16(Wo[k][a])  (identical to round 2)
// ---------------------------------------------------------------------------
__global__ __launch_bounds__(256) void kT(const float* __restrict__ Wo, u16* __restrict__ WoT) {
  __shared__ __align__(16) u16 t[64 * 72];
  const int b = blockIdx.x;
  const int tid = threadIdx.x;
  {
    int k = tid >> 2, a0 = (tid & 3) * 16;
    const float* src = &Wo[(size_t)(b * 64 + k) * 64 + a0];
#pragma unroll
    for (int q = 0; q < 4; ++q) {
      f32x4 v = *(const f32x4*)&src[q * 4];
#pragma unroll
      for (int e = 0; e < 4; ++e) t[k * 72 + a0 + q * 4 + e] = f2b(v[e]);
    }
  }
  __syncthreads();
  {
    int a = tid >> 2, k0 = (tid & 3) * 16;
    u16x8 o0, o1;
#pragma unroll
    for (int j = 0; j < 8; ++j) o0[j] = t[(k0 + j) * 72 + a];
#pragma unroll
    for (int j = 0; j < 8; ++j) o1[j] = t[(k0 + 8 + j) * 72 + a];
    *(u16x8*)&WoT[(size_t)a * 4096 + b * 64 + k0] = o0;
    *(u16x8*)&WoT[(size_t)a * 4096 + b * 64 + k0 + 8] = o1;
  }
}

// ---------------------------------------------------------------------------
// gemm_n64 (identical to round 2)
// ---------------------------------------------------------------------------
#define PBK 128
__device__ void gemm_n64(const u16* __restrict__ A, const u16* __restrict__ B,
                         u16* __restrict__ C, const float* __restrict__ bias,
                         long m0, u16* lA, u16* lB) {
  const int tid = threadIdx.x;
  const int w = tid >> 6, l = tid & 63;
  f32x4 acc[4];
#pragma unroll
  for (int nt = 0; nt < 4; ++nt) acc[nt] = (f32x4)(0.f);

  for (int k0 = 0; k0 < 4096; k0 += PBK) {
    __syncthreads();
#pragma unroll
    for (int i = 0; i < 4; ++i) {
      int row = w * 16 + i * 4 + (l >> 4);
      int p = (l & 15) ^ (i * 4 + (l >> 4));
      gl_lds16(A + (m0 + row) * (long)4096 + k0 + p * 8, lA + (w * 16 + i * 4) * PBK);
      gl_lds16(B + (long)row * 4096 + k0 + p * 8, lB + (w * 16 + i * 4) * PBK);
    }
    __syncthreads();
#pragma unroll
    for (int kk = 0; kk < 4; ++kk) {
      int slotA = ((kk * 4 + (l >> 4)) ^ (l & 15)) * 8;
      bf16x8 af = *(const bf16x8*)&lA[(w * 16 + (l & 15)) * PBK + slotA];
#pragma unroll
      for (int nt = 0; nt < 4; ++nt) {
        bf16x8 bf = *(const bf16x8*)&lB[(nt * 16 + (l & 15)) * PBK + slotA];
        acc[nt] = mfma16(af, bf, acc[nt]);
      }
    }
  }
#pragma unroll
  for (int nt = 0; nt < 4; ++nt) {
    int col = nt * 16 + (l & 15);
    float bb = bias ? bias[col] : 0.f;
#pragma unroll
    for (int r = 0; r < 4; ++r) {
      long row = m0 + w * 16 + (l >> 4) * 4 + r;
      C[row * 64 + col] = f2b(acc[nt][r] + bb);
    }
  }
}

// ---------------------------------------------------------------------------
// k_prep (identical to round 2)
// ---------------------------------------------------------------------------
__global__ __launch_bounds__(256, 2) void k_prep(
    const u16* __restrict__ xb, const u16* __restrict__ Wvb, const float* __restrict__ bv,
    const u16* __restrict__ Wnb, const u16* __restrict__ WoT,
    const float* __restrict__ bo, const float* __restrict__ bn,
    u16* __restrict__ V, u16* __restrict__ Wm, float* __restrict__ biasTot) {
  __shared__ __align__(16) u16 lA[64 * PBK];
  __shared__ __align__(16) u16 lB[64 * PBK];
  const int bid = blockIdx.x;
  if (bid < 128) {
    gemm_n64(xb, Wvb, V, bv, (long)bid * 64, lA, lB);
  } else if (bid < 192) {
    gemm_n64(Wnb, WoT, Wm, nullptr, (long)(bid - 128) * 64, lA, lB);
  } else {
    const int w = threadIdx.x >> 6, l = threadIdx.x & 63;
    const int n = (bid - 192) * 4 + w;
    float s = 0.f;
#pragma unroll
    for (int j = 0; j < 8; ++j) {
      int off = (j * 64 + l) * 8;
      u16x8 a = *(const u16x8*)&Wnb[(size_t)n * 4096 + off];
      f32x4 c0 = *(const f32x4*)&bo[off];
      f32x4 c1 = *(const f32x4*)&bo[off + 4];
#pragma unroll
      for (int e = 0; e < 4; ++e) s += b2f(a[e]) * c0[e] + b2f(a[4 + e]) * c1[e];
    }
#pragma unroll
    for (int o = 32; o > 0; o >>= 1) s += __shfl_xor(s, o, 64);
    if (l == 0) biasTot[n] = s + bn[n];
  }
}

// ---------------------------------------------------------------------------
// k_main (ROUND-5 REWRITE): 256x256 tile, 512 threads, 8-phase deep pipeline.
//   LDS ring: 4 slices, slice q at smem + q*16384 elems:
//     A region [0,8192): 256 rows x 32 elems (64B rows, 4 x 16B slots)
//     B region [8192,16384): same
//   Swizzle: LDS[row][s] = global[row][s ^ ((row>>1)&3)]  (s = 16B slot 0..3)
//     stage: lane l -> row l>>2 (16-row group), LDS slot l&3,
//            global slot (l&3) ^ ((l>>3)&3)
//     read : frag row r = base16 + (l&15), global slot g = l>>4,
//            LDS slot g ^ ((l>>1)&3)   -> bank-balanced (8 lanes / 4-bank grp)
//   Slices 0..127 = X/Wn K-panels (lda 4096); 128,129 = V/Wm (lda 64).
//   Pipeline: slice s+2 issued during slice s (A in phase 0, B in phase 1);
//   boundary wait vmcnt(4) keeps 4 loads in flight; vmcnt(0) only at s=128.
// ---------------------------------------------------------------------------
__global__ __launch_bounds__(512, 2) void k_main(
    const u16* __restrict__ X, const u16* __restrict__ Wn,
    const u16* __restrict__ V, const u16* __restrict__ Wm,
    const float* __restrict__ biasTot, float* __restrict__ Out) {
  __shared__ __align__(16) u16 smem[4 * 16384];  // 128 KB
  const int tid = threadIdx.x;
  const int w = tid >> 6, l = tid & 63;
  const int wm = w >> 2, wn = w & 3;
  const long mBase = (long)(blockIdx.x >> 4) * 256;
  const int  nBase = (int)(blockIdx.x & 15) * 256;

  // ---- staging constants (per thread)
  const int rs  = l >> 2;                             // row within 16-row op
  const int gsl = ((l & 3) ^ ((l >> 3) & 3)) * 8;     // pre-swizzled global slot (elems)
  const long rA = mBase + w * 16 + rs;
  const long rB = nBase + w * 16 + rs;
  const u16* xA0 = X  + rA * 4096 + gsl;
  const u16* xA1 = xA0 + 128L * 4096;
  const u16* nB0 = Wn + rB * 4096 + gsl;
  const u16* nB1 = nB0 + 128L * 4096;
  const u16* vA0 = V  + rA * 64 + gsl;
  const u16* vA1 = vA0 + 128 * 64;
  const u16* wB0 = Wm + rB * 64 + gsl;
  const u16* wB1 = wB0 + 128 * 64;
  const int dA0 = w * 512;            // (w*16 rows)*32 elems
  const int dA1 = 4096 + dA0;         // rows 128..255
  const int dB0 = 8192 + dA0, dB1 = 8192 + dA1;

  // ---- fragment-read constants
  const int frow = l & 15;
  const int sxor = ((l >> 4) ^ ((l >> 1) & 3)) * 8;   // swizzled slot (elems)
  const int aoffA = (wm * 128 + frow) * 32 + sxor;
  const int aoffB = 8192 + (wn * 64 + frow) * 32 + sxor;

  f32x4 acc[8][4];
#pragma unroll
  for (int mt = 0; mt < 8; ++mt)
#pragma unroll
    for (int nt = 0; nt < 4; ++nt) acc[mt][nt] = (f32x4)(0.f);

  // ---- prologue: stage slices 0,1 (slots 0,1); A,A,B,B order per slice
  gl_lds16(xA0,      smem + dA0);
  gl_lds16(xA1,      smem + dA1);
  gl_lds16(nB0,      smem + dB0);
  gl_lds16(nB1,      smem + dB1);
  gl_lds16(xA0 + 32, smem + 16384 + dA0);
  gl_lds16(xA1 + 32, smem + 16384 + dA1);
  gl_lds16(nB0 + 32, smem + 16384 + dB0);
  gl_lds16(nB1 + 32, smem + 16384 + dB1);
  asm volatile("s_waitcnt vmcnt(4)" ::: "memory");  // slice 0 landed
  __builtin_amdgcn_s_barrier();

  bf16x8 af[4], bq[4];
  for (int s = 0; s < 130; ++s) {
    const int qb = (s & 3) * 16384;
    const int t = s + 2;
    const int qs = (t & 3) * 16384;
    const long ko = (long)t * 32;
    // ---------------- phase 0: read A[0..3],B[0..3]; stage A of slice t
#pragma unroll
    for (int i = 0; i < 4; ++i) af[i] = *(const bf16x8*)&smem[qb + aoffA + i * 512];
#pragma unroll
    for (int i = 0; i < 4; ++i) bq[i] = *(const bf16x8*)&smem[qb + aoffB + i * 512];
    if (t < 128) {
      gl_lds16(xA0 + ko, smem + qs + dA0);
      gl_lds16(xA1 + ko, smem + qs + dA1);
    } else if (t < 130) {
      const long kv = (long)(t - 128) * 32;
      gl_lds16(vA0 + kv, smem + qs + dA0);
      gl_lds16(vA1 + kv, smem + qs + dA1);
    }
    __builtin_amdgcn_s_barrier();
    asm volatile("s_waitcnt lgkmcnt(0)" ::: "memory");
    __builtin_amdgcn_sched_barrier(0);
    __builtin_amdgcn_s_setprio(1);
#pragma unroll
    for (int mt = 0; mt < 4; ++mt)
#pragma unroll
      for (int nt = 0; nt < 4; ++nt) acc[mt][nt] = mfma16(af[mt], bq[nt], acc[mt][nt]);
    __builtin_amdgcn_s_setprio(0);
    __builtin_amdgcn_sched_barrier(0);
    __builtin_amdgcn_s_barrier();
    // ---------------- phase 1: read A[4..7] (reuse B); stage B of slice t
#pragma unroll
    for (int i = 0; i < 4; ++i) af[i] = *(const bf16x8*)&smem[qb + aoffA + (4 + i) * 512];
    if (t < 128) {
      gl_lds16(nB0 + ko, smem + qs + dB0);
      gl_lds16(nB1 + ko, smem + qs + dB1);
    } else if (t < 130) {
      const long kv = (long)(t - 128) * 32;
      gl_lds16(wB0 + kv, smem + qs + dB0);
      gl_lds16(wB1 + kv, smem + qs + dB1);
    }
    __builtin_amdgcn_s_barrier();
    asm volatile("s_waitcnt lgkmcnt(0)" ::: "memory");
    __builtin_amdgcn_sched_barrier(0);
    __builtin_amdgcn_s_setprio(1);
#pragma unroll
    for (int mt = 0; mt < 4; ++mt)
#pragma unroll
      for (int nt = 0; nt < 4; ++nt) acc[4 + mt][nt] = mfma16(af[mt], bq[nt], acc[4 + mt][nt]);
    __builtin_amdgcn_s_setprio(0);
    __builtin_amdgcn_sched_barrier(0);
    // ---------------- slice-boundary wait: counted, never 0 until tail
    if (s < 128) {
      asm volatile("s_waitcnt vmcnt(4)" ::: "memory");  // slice s+1 landed
    } else if (s == 128) {
      asm volatile("s_waitcnt vmcnt(0)" ::: "memory");  // drain tail (slice 129)
    }
    __builtin_amdgcn_s_barrier();
  }

  // ---- epilogue: bias + relu, fp32; per-wave LDS transpose (4 KB/wave)
  __syncthreads();
  float* eb = ((float*)smem) + w * 1024;
  const int wRow = wm * 128, wCol = wn * 64;
  float bt[4];
#pragma unroll
  for (int nt = 0; nt < 4; ++nt) bt[nt] = biasTot[nBase + wCol + nt * 16 + frow];
#pragma unroll
  for (int mt = 0; mt < 8; ++mt) {
#pragma unroll
    for (int nt = 0; nt < 4; ++nt) {
#pragma unroll
      for (int r = 0; r < 4; ++r) {
        float val = acc[mt][nt][r] + bt[nt];
        eb[((l >> 4) * 4 + r) * 64 + nt * 16 + frow] = fmaxf(val, 0.f);
      }
    }
    int rr = l >> 2, c0 = (l & 3) * 16;
    long grow = mBase + wRow + mt * 16 + rr;
    int gcol = nBase + wCol + c0;
    f32x4 o0 = *(const f32x4*)&eb[rr * 64 + c0];
    f32x4 o1 = *(const f32x4*)&eb[rr * 64 + c0 + 4];
    f32x4 o2 = *(const f32x4*)&eb[rr * 64 + c0 + 8];
    f32x4 o3 = *(const f32x4*)&eb[rr * 64 + c0 + 12];
    *(f32x4*)&Out[grow * 4096 + gcol] = o0;
    *(f32x4*)&Out[grow * 4096 + gcol + 4] = o1;
    *(f32x4*)&Out[grow * 4096 + gcol + 8] = o2;
    *(f32x4*)&Out[grow * 4096 + gcol + 12] = o3;
  }
}

// ---------------------------------------------------------------------------
extern "C" void kernel_launch(void* const* d_in, const int* in_sizes, int n_in,
                              void* d_out, int out_size, void* d_ws, size_t ws_size,
                              hipStream_t stream) {
  const float* x  = (const float*)d_in[0];
  const float* Wv = (const float*)d_in[5];
  const float* bv = (const float*)d_in[6];
  const float* Wo = (const float*)d_in[7];
  const float* bo = (const float*)d_in[8];
  const float* Wn = (const float*)d_in[9];
  const float* bn = (const float*)d_in[10];
  float* out = (float*)d_out;

  char* ws = (char*)d_ws;
  u16* xb  = (u16*)ws;                             // 8192*4096*2 = 64 MB
  u16* Wnb = (u16*)(ws + (64L << 20));             // 4096*4096*2 = 32 MB
  u16* Wvb = (u16*)(ws + (96L << 20));             // 64*4096*2   = 512 KB
  u16* WoT = (u16*)(ws + (96L << 20) + (512 << 10));   // 512 KB
  u16* V   = (u16*)(ws + (97L << 20));             // 8192*64*2   = 1 MB
  u16* Wm  = (u16*)(ws + (98L << 20));             // 4096*64*2   = 512 KB
  float* biasTot = (float*)(ws + (98L << 20) + (512 << 10));  // 16 KB

  k_cvt<<<dim3(24704), dim3(256), 0, stream>>>(x, Wn, Wv, xb, Wnb, Wvb);
  kT<<<dim3(64), dim3(256), 0, stream>>>(Wo, WoT);
  k_prep<<<dim3(1216), dim3(256), 0, stream>>>(xb, Wvb, bv, Wnb, WoT, bo, bn, V, Wm, biasTot);
  k_main<<<dim3(512), dim3(512), 0, stream>>>(xb, Wnb, V, Wm, biasTot, out);
}

// Round 2
// 603.422 us; speedup vs baseline: 1.0182x; 1.0182x over previous
//
#include <hip/hip_runtime.h>
#include <stdint.h>

// Problem (fp32 in / fp32 out): out = relu((x + (x@Wv^T+bv)@Wo^T + bo) @ Wn^T + bn)
//   softmax over a single score == 1 -> q,k path is dead code.
// Reformulated: out = relu(x@Wn^T + v@Wm^T + biasTot)
//   v  = x@Wv^T + bv          [8192 x 64]
//   Wm = Wn @ Wo              [4096 x 64]
//   biasTot = bn + Wn @ bo    [4096]
// Round 6: REVERT k_main to round-4 structure (proven 268.6us, MfmaUtil 49%,
//   ~3 blocks/CU inter-block overlap) -- round-5's 128KB 8-phase ring dropped
//   occupancy to 1 block/CU and regressed to 39% util.
// Changes vs round-4:
//   (1) k_main: bijective XCD-chunked blockIdx swizzle (T1). Each XCD owns
//       8 m-tiles; within an XCD blocks sweep n-pairs with m inner ->
//       B-panel pairs stay L2-resident per XCD, A re-reads hit L3.
//       Targets the single-buffer staging-drain latency (FETCH 412MB -> ~250).
//   (2) k_cvt + kT fused into one dispatch (independent outputs) -- removes
//       one kernel-serialization gap.

typedef unsigned short u16;
typedef float f32x4 __attribute__((ext_vector_type(4)));
typedef __bf16 bf16x8 __attribute__((ext_vector_type(8)));
typedef u16 u16x8 __attribute__((ext_vector_type(8)));

__device__ __forceinline__ float b2f(u16 u) {
  union { unsigned int i; float f; } x; x.i = ((unsigned int)u) << 16; return x.f;
}
__device__ __forceinline__ u16 f2b(float f) {  // round-to-nearest-even
  union { float f; unsigned int i; } x; x.f = f;
  unsigned int r = x.i + 0x7FFFu + ((x.i >> 16) & 1u);
  return (u16)(r >> 16);
}

// async global->LDS, 16B per lane; lds base wave-uniform (lane lands at base + lane*16B)
__device__ __forceinline__ void gl_lds16(const u16* g, u16* l) {
#if __has_builtin(__builtin_amdgcn_global_load_lds)
  __builtin_amdgcn_global_load_lds((__attribute__((address_space(1))) void*)g,
                                   (__attribute__((address_space(3))) void*)l, 16, 0, 0);
#else
  int lane = threadIdx.x & 63;
  *(u16x8*)(l + lane * 8) = *(const u16x8*)g;
#endif
}

__device__ __forceinline__ f32x4 mfma16(bf16x8 a, bf16x8 b, f32x4 c) {
  return __builtin_amdgcn_mfma_f32_16x16x32_bf16(a, b, c, 0, 0, 0);
}

// ---------------------------------------------------------------------------
// k_pre: fused  (a) fp32->bf16 for x (33.5M), Wn (16.7M), Wv (262K), 8/thread
//               (b) WoT[a][k] = bf16(Wo[k][a])   (64 tail blocks)
// ---------------------------------------------------------------------------
#define XCH 4194304L   // 33554432/8
#define WNCH 2097152L  // 16777216/8
#define CVTB 24704     // cvt blocks
__global__ __launch_bounds__(256) void k_pre(
    const float* __restrict__ x, const float* __restrict__ Wn, const float* __restrict__ Wv,
    u16* __restrict__ xb, u16* __restrict__ Wnb, u16* __restrict__ Wvb,
    const float* __restrict__ Wo, u16* __restrict__ WoT) {
  if (blockIdx.x < CVTB) {
    long i = (long)blockIdx.x * 256 + threadIdx.x;
    const float* src; u16* dst; long off;
    if (i < XCH) { src = x; dst = xb; off = i * 8; }
    else if (i < XCH + WNCH) { src = Wn; dst = Wnb; off = (i - XCH) * 8; }
    else { src = Wv; dst = Wvb; off = (i - XCH - WNCH) * 8; }
    f32x4 a = *(const f32x4*)&src[off];
    f32x4 b = *(const f32x4*)&src[off + 4];
    u16x8 o;
#pragma unroll
    for (int e = 0; e < 4; ++e) { o[e] = f2b(a[e]); o[4 + e] = f2b(b[e]); }
    *(u16x8*)&dst[off] = o;
  } else {
    __shared__ __align__(16) u16 t[64 * 72];
    const int b = blockIdx.x - CVTB;
    const int tid = threadIdx.x;
    {
      int k = tid >> 2, a0 = (tid & 3) * 16;
      const float* src = &Wo[(size_t)(b * 64 + k) * 64 + a0];
#pragma unroll
      for (int q = 0; q < 4; ++q) {
        f32x4 v = *(const f32x4*)&src[q * 4];
#pragma unroll
        for (int e = 0; e < 4; ++e) t[k * 72 + a0 + q * 4 + e] = f2b(v[e]);
      }
    }
    __syncthreads();
    {
      int a = tid >> 2, k0 = (tid & 3) * 16;
      u16x8 o0, o1;
#pragma unroll
      for (int j = 0; j < 8; ++j) o0[j] = t[(k0 + j) * 72 + a];
#pragma unroll
      for (int j = 0; j < 8; ++j) o1[j] = t[(k0 + 8 + j) * 72 + a];
      *(u16x8*)&WoT[(size_t)a * 4096 + b * 64 + k0] = o0;
      *(u16x8*)&WoT[(size_t)a * 4096 + b * 64 + k0 + 8] = o1;
    }
  }
}

// ---------------------------------------------------------------------------
// gemm_n64 (identical to round 2)
// ---------------------------------------------------------------------------
#define PBK 128
__device__ void gemm_n64(const u16* __restrict__ A, const u16* __restrict__ B,
                         u16* __restrict__ C, const float* __restrict__ bias,
                         long m0, u16* lA, u16* lB) {
  const int tid = threadIdx.x;
  const int w = tid >> 6, l = tid & 63;
  f32x4 acc[4];
#pragma unroll
  for (int nt = 0; nt < 4; ++nt) acc[nt] = (f32x4)(0.f);

  for (int k0 = 0; k0 < 4096; k0 += PBK) {
    __syncthreads();
#pragma unroll
    for (int i = 0; i < 4; ++i) {
      int row = w * 16 + i * 4 + (l >> 4);
      int p = (l & 15) ^ (i * 4 + (l >> 4));
      gl_lds16(A + (m0 + row) * (long)4096 + k0 + p * 8, lA + (w * 16 + i * 4) * PBK);
      gl_lds16(B + (long)row * 4096 + k0 + p * 8, lB + (w * 16 + i * 4) * PBK);
    }
    __syncthreads();
#pragma unroll
    for (int kk = 0; kk < 4; ++kk) {
      int slotA = ((kk * 4 + (l >> 4)) ^ (l & 15)) * 8;
      bf16x8 af = *(const bf16x8*)&lA[(w * 16 + (l & 15)) * PBK + slotA];
#pragma unroll
      for (int nt = 0; nt < 4; ++nt) {
        bf16x8 bf = *(const bf16x8*)&lB[(nt * 16 + (l & 15)) * PBK + slotA];
        acc[nt] = mfma16(af, bf, acc[nt]);
      }
    }
  }
#pragma unroll
  for (int nt = 0; nt < 4; ++nt) {
    int col = nt * 16 + (l & 15);
    float bb = bias ? bias[col] : 0.f;
#pragma unroll
    for (int r = 0; r < 4; ++r) {
      long row = m0 + w * 16 + (l >> 4) * 4 + r;
      C[row * 64 + col] = f2b(acc[nt][r] + bb);
    }
  }
}

// ---------------------------------------------------------------------------
// k_prep (identical to round 2)
// ---------------------------------------------------------------------------
__global__ __launch_bounds__(256, 2) void k_prep(
    const u16* __restrict__ xb, const u16* __restrict__ Wvb, const float* __restrict__ bv,
    const u16* __restrict__ Wnb, const u16* __restrict__ WoT,
    const float* __restrict__ bo, const float* __restrict__ bn,
    u16* __restrict__ V, u16* __restrict__ Wm, float* __restrict__ biasTot) {
  __shared__ __align__(16) u16 lA[64 * PBK];
  __shared__ __align__(16) u16 lB[64 * PBK];
  const int bid = blockIdx.x;
  if (bid < 128) {
    gemm_n64(xb, Wvb, V, bv, (long)bid * 64, lA, lB);
  } else if (bid < 192) {
    gemm_n64(Wnb, WoT, Wm, nullptr, (long)(bid - 128) * 64, lA, lB);
  } else {
    const int w = threadIdx.x >> 6, l = threadIdx.x & 63;
    const int n = (bid - 192) * 4 + w;
    float s = 0.f;
#pragma unroll
    for (int j = 0; j < 8; ++j) {
      int off = (j * 64 + l) * 8;
      u16x8 a = *(const u16x8*)&Wnb[(size_t)n * 4096 + off];
      f32x4 c0 = *(const f32x4*)&bo[off];
      f32x4 c1 = *(const f32x4*)&bo[off + 4];
#pragma unroll
      for (int e = 0; e < 4; ++e) s += b2f(a[e]) * c0[e] + b2f(a[4 + e]) * c1[e];
    }
#pragma unroll
    for (int o = 32; o > 0; o >>= 1) s += __shfl_xor(s, o, 64);
    if (l == 0) biasTot[n] = s + bn[n];
  }
}

// ---------------------------------------------------------------------------
// k_main (round-4 structure, proven): BK=64, XOR-swizzled LDS (128B rows),
//   64 main iters + 1 tail iter (V/Wm, K=64). 128x128 tile, 4 waves 2x2,
//   gl_lds16 staging, fp32 out via per-wave LDS transpose. LDS 32 KB.
// ROUND-6 CHANGE: bijective XCD-chunked tile mapping (grid 2048 = 8 XCD x 256):
//   xcd = bid&7 (round-robin dispatch), j = bid>>3 in [0,256)
//   mT = xcd*8 + ((j>>1)&7)   -- each XCD owns 8 m-tiles (A partitioned)
//   nT = (j>>4)*2 + (j&1)     -- n-pairs swept with m inner -> B-pair L2-hot
// ---------------------------------------------------------------------------
__global__ __launch_bounds__(256, 2) void k_main(
    const u16* __restrict__ X, const u16* __restrict__ Wn,
    const u16* __restrict__ V, const u16* __restrict__ Wm,
    const float* __restrict__ biasTot, float* __restrict__ Out) {
  __shared__ __align__(16) u16 smem[2 * 128 * 64];  // 32 KB
  u16* lA = smem;
  u16* lB = smem + 128 * 64;
  const int tid = threadIdx.x;
  const int w = tid >> 6, l = tid & 63;
  const int wRow = (w & 1) * 64, wCol = (w >> 1) * 64;
  const int xcd = (int)(blockIdx.x & 7);
  const int j   = (int)(blockIdx.x >> 3);        // 0..255 within XCD
  const int mT  = xcd * 8 + ((j >> 1) & 7);      // 0..63
  const int nT  = (j >> 4) * 2 + (j & 1);        // 0..31
  const long mBase = (long)mT * 128;
  const int  nBase = nT * 128;

  f32x4 acc[4][4];
#pragma unroll
  for (int mt = 0; mt < 4; ++mt)
#pragma unroll
    for (int nt = 0; nt < 4; ++nt) acc[mt][nt] = (f32x4)(0.f);

  const int srow = l >> 3;            // staging sub-row 0..7
  const int sp = ((l & 7) ^ srow) * 8;  // swizzled global 16B-slot (elements)

  for (int kb = 0; kb < 65; ++kb) {
    const u16 *pA, *pB; long lda;
    if (kb < 64) { pA = X + (long)kb * 64; pB = Wn + (long)kb * 64; lda = 4096; }
    else         { pA = V;                 pB = Wm;                 lda = 64;  }
    __syncthreads();
#pragma unroll
    for (int i = 0; i < 4; ++i) {
      int row = w * 32 + i * 8 + srow;
      gl_lds16(pA + (mBase + row) * lda + sp, lA + (w * 32 + i * 8) * 64);
      gl_lds16(pB + (long)(nBase + row) * lda + sp, lB + (w * 32 + i * 8) * 64);
    }
    __syncthreads();
#pragma unroll
    for (int kk = 0; kk < 2; ++kk) {
      int slot = ((kk * 4 + (l >> 4)) ^ (l & 7)) * 8;
      bf16x8 af[4], bfr[4];
#pragma unroll
      for (int mt = 0; mt < 4; ++mt)
        af[mt] = *(const bf16x8*)&lA[(wRow + mt * 16 + (l & 15)) * 64 + slot];
#pragma unroll
      for (int nt = 0; nt < 4; ++nt)
        bfr[nt] = *(const bf16x8*)&lB[(wCol + nt * 16 + (l & 15)) * 64 + slot];
#pragma unroll
      for (int mt = 0; mt < 4; ++mt)
#pragma unroll
        for (int nt = 0; nt < 4; ++nt) acc[mt][nt] = mfma16(af[mt], bfr[nt], acc[mt][nt]);
    }
  }

  // epilogue: bias + relu, fp32; per-wave LDS transpose (4 KB/wave), dwordx4 stores
  __syncthreads();
  float* eb = ((float*)smem) + w * 1024;
#pragma unroll
  for (int mt = 0; mt < 4; ++mt) {
#pragma unroll
    for (int nt = 0; nt < 4; ++nt) {
      float bt = biasTot[nBase + wCol + nt * 16 + (l & 15)];
#pragma unroll
      for (int r = 0; r < 4; ++r) {
        float val = acc[mt][nt][r] + bt;
        eb[((l >> 4) * 4 + r) * 64 + nt * 16 + (l & 15)] = fmaxf(val, 0.f);
      }
    }
    int rr = l >> 2, c0 = (l & 3) * 16;
    long grow = mBase + wRow + mt * 16 + rr;
    int gcol = nBase + wCol + c0;
    f32x4 o0 = *(const f32x4*)&eb[rr * 64 + c0];
    f32x4 o1 = *(const f32x4*)&eb[rr * 64 + c0 + 4];
    f32x4 o2 = *(const f32x4*)&eb[rr * 64 + c0 + 8];
    f32x4 o3 = *(const f32x4*)&eb[rr * 64 + c0 + 12];
    *(f32x4*)&Out[grow * 4096 + gcol] = o0;
    *(f32x4*)&Out[grow * 4096 + gcol + 4] = o1;
    *(f32x4*)&Out[grow * 4096 + gcol + 8] = o2;
    *(f32x4*)&Out[grow * 4096 + gcol + 12] = o3;
  }
}

// ---------------------------------------------------------------------------
extern "C" void kernel_launch(void* const* d_in, const int* in_sizes, int n_in,
                              void* d_out, int out_size, void* d_ws, size_t ws_size,
                              hipStream_t stream) {
  const float* x  = (const float*)d_in[0];
  const float* Wv = (const float*)d_in[5];
  const float* bv = (const float*)d_in[6];
  const float* Wo = (const float*)d_in[7];
  const float* bo = (const float*)d_in[8];
  const float* Wn = (const float*)d_in[9];
  const float* bn = (const float*)d_in[10];
  float* out = (float*)d_out;

  char* ws = (char*)d_ws;
  u16* xb  = (u16*)ws;                             // 8192*4096*2 = 64 MB
  u16* Wnb = (u16*)(ws + (64L << 20));             // 4096*4096*2 = 32 MB
  u16* Wvb = (u16*)(ws + (96L << 20));             // 64*4096*2   = 512 KB
  u16* WoT = (u16*)(ws + (96L << 20) + (512 << 10));   // 512 KB
  u16* V   = (u16*)(ws + (97L << 20));             // 8192*64*2   = 1 MB
  u16* Wm  = (u16*)(ws + (98L << 20));             // 4096*64*2   = 512 KB
  float* biasTot = (float*)(ws + (98L << 20) + (512 << 10));  // 16 KB

  k_pre<<<dim3(CVTB + 64), dim3(256), 0, stream>>>(x, Wn, Wv, xb, Wnb, Wvb, Wo, WoT);
  k_prep<<<dim3(1216), dim3(256), 0, stream>>>(xb, Wvb, bv, Wnb, WoT, bo, bn, V, Wm, biasTot);
  k_main<<<dim3(2048), dim3(256), 0, stream>>>(xb, Wnb, V, Wm, biasTot, out);
}